// Round 7
// baseline (285.931 us; speedup 1.0000x reference)
//
#include <hip/hip_runtime.h>

#define N_NODES 100000
#define E_EDGES 1600000
#define DIM     128

// Binning geometry:
//  coarse bucket = 256 nodes (dst>>8): 391 real buckets, padded 512
//  chunk = 8192 edges: 196 chunks
#define NB1     196            // level-1 chunks (8192 edges each)
#define CHUNK   8192
#define NBINS   512            // padded bucket count (actual 391)
#define NBUCKET 391
#define NBH     (NBINS * NB1)  // 100352 bin-major [bin][chunk] histogram entries
#define HS_BLOCKS 98           // NBH / 1024 exactly

// Workspace layout (bytes), total ~39.3 MiB:
#define HB_OFF    0            // h packed bf16: N*64 u32 = 25,600,000
#define WTB_OFF   25600000     // WcatT bf16 B-fragment layout: 16384 u32 = 65,536
#define OFFS_OFF  25665536     // N+1 int (padded to 400,064)
#define BH_OFF    26065600     // NBH ints = 401,408
#define BSUM_OFF  26467008     // 98 ints (padded to 1024)
#define BIN_OFF   26468032     // E ints = 6,400,000
#define SRC_OFF   32868032     // E ints = 6,400,000 -> end 39,268,032

typedef __attribute__((ext_vector_type(8))) short short8;
typedef __attribute__((ext_vector_type(4))) float floatx4;

// ---------- bf16 pack/unpack (RNE) ----------
__device__ __forceinline__ unsigned bf16pack(float a, float b) {
  unsigned ua = __float_as_uint(a); ua += 0x7fffu + ((ua >> 16) & 1u);
  unsigned ub = __float_as_uint(b); ub += 0x7fffu + ((ub >> 16) & 1u);
  return (ua >> 16) | (ub & 0xffff0000u);
}
__device__ __forceinline__ float2 bf16unpack(unsigned p) {
  return make_float2(__uint_as_float(p << 16), __uint_as_float(p & 0xffff0000u));
}

// ------------- prep: LayerNorm+ReLU -> hb, weight pack, level-1 histogram ----
__global__ __launch_bounds__(256) void k_prep(const float* __restrict__ x,
                                              const float* __restrict__ lw,
                                              const float* __restrict__ lb,
                                              const float* __restrict__ Wl,
                                              const float* __restrict__ Wr,
                                              const int* __restrict__ ei,
                                              unsigned* __restrict__ hb,
                                              unsigned* __restrict__ wtb,
                                              int* __restrict__ bh) {
  int gid = blockIdx.x * 256 + threadIdx.x;
  int t = threadIdx.x;

  // --- LN+ReLU ---
  {
    int row  = blockIdx.x * 4 + (t >> 6);
    int lane = t & 63;
    float2 v = ((const float2*)(x + (size_t)row * DIM))[lane];
    float s  = v.x + v.y;
    float sq = v.x * v.x + v.y * v.y;
    #pragma unroll
    for (int off = 32; off > 0; off >>= 1) {
      s  += __shfl_xor(s, off);
      sq += __shfl_xor(sq, off);
    }
    float mu  = s * (1.0f / 128.0f);
    float var = sq * (1.0f / 128.0f) - mu * mu;
    float rs  = rsqrtf(var + 1e-5f);
    float2 w = ((const float2*)lw)[lane];
    float2 b = ((const float2*)lb)[lane];
    float ox = fmaxf((v.x - mu) * rs * w.x + b.x, 0.0f);
    float oy = fmaxf((v.y - mu) * rs * w.y + b.y, 0.0f);
    hb[(size_t)row * 64 + lane] = bf16pack(ox, oy);
  }

  // --- weight pack (bf16, B-fragment layout) ---
  if (gid < 16384) {
    int j2 = gid & 3;
    int q  = (gid >> 2) & 3;
    int c  = (gid >> 4) & 127;
    int kb = gid >> 11;
    int k0 = kb * 32 + q * 8 + j2 * 2;
    int k1 = k0 + 1;
    float v0 = (k0 < 128) ? Wl[c * 128 + k0] : Wr[c * 128 + (k0 - 128)];
    float v1 = (k1 < 128) ? Wl[c * 128 + k1] : Wr[c * 128 + (k1 - 128)];
    wtb[gid] = bf16pack(v0, v1);
  }

  // --- level-1 histogram: chunk = 8192 edges (block-uniform branch) ---
  if (blockIdx.x < NB1) {
    __shared__ int h[NBINS];
    h[t] = 0; h[t + 256] = 0;
    __syncthreads();
    const int4* d4p = (const int4*)(ei + E_EDGES);
    #pragma unroll
    for (int u = 0; u < 8; ++u) {
      int i4 = blockIdx.x * (CHUNK / 4) + u * 256 + t;
      if (i4 < E_EDGES / 4) {
        int4 d = d4p[i4];
        atomicAdd(&h[d.x >> 8], 1);
        atomicAdd(&h[d.y >> 8], 1);
        atomicAdd(&h[d.z >> 8], 1);
        atomicAdd(&h[d.w >> 8], 1);
      }
    }
    __syncthreads();
    bh[t * NB1 + blockIdx.x] = h[t];
    bh[(t + 256) * NB1 + blockIdx.x] = h[t + 256];
  }
}

// ---------------- scan stage 1 over bh (in-place, 1024 elems/block) ----------
// Leaves bh as block-local exclusive scans; bsum holds the 98 block totals.
// (Stage-2 base-add is folded into binsort/csr via an LDS bsum scan.)
__global__ __launch_bounds__(256) void k_hscan1(int* __restrict__ bh,
                                                int* __restrict__ bsum) {
  __shared__ int s[256];
  int t = threadIdx.x;
  int base = blockIdx.x * 1024 + t * 4;
  int a0 = (base + 0 < NBH) ? bh[base + 0] : 0;
  int a1 = (base + 1 < NBH) ? bh[base + 1] : 0;
  int a2 = (base + 2 < NBH) ? bh[base + 2] : 0;
  int a3 = (base + 3 < NBH) ? bh[base + 3] : 0;
  s[t] = a0 + a1 + a2 + a3;
  __syncthreads();
  #pragma unroll
  for (int off = 1; off < 256; off <<= 1) {
    int x = (t >= off) ? s[t - off] : 0;
    __syncthreads();
    s[t] += x;
    __syncthreads();
  }
  int excl = (t > 0) ? s[t - 1] : 0;
  if (t == 255) bsum[blockIdx.x] = s[255];
  if (base + 0 < NBH) bh[base + 0] = excl;
  if (base + 1 < NBH) bh[base + 1] = excl + a0;
  if (base + 2 < NBH) bh[base + 2] = excl + a0 + a1;
  if (base + 3 < NBH) bh[base + 3] = excl + a0 + a1 + a2;
}

// ------- level-1 bin-sort: LDS-sorted chunk, COALESCED write-out -------------
// Scans the 98 bsum partials in LDS (replaces k_hscan2), then:
//  pass1 LDS hist -> LDS scan -> pass2 place into stage[]+addr[] -> stream out.
__global__ __launch_bounds__(256) void k_binsort(const int* __restrict__ ei,
                                                 const int* __restrict__ bh,
                                                 const int* __restrict__ bsum,
                                                 int* __restrict__ binned) {
  __shared__ int stage[CHUNK];   // 32 KiB: bin-sorted packed edges
  __shared__ int addr[CHUNK];    // 32 KiB: final global index per staged edge
  __shared__ int hist[NBINS];
  __shared__ int ebase[NBINS];   // intra-chunk exclusive base per bin
  __shared__ int cur[NBINS];     // placement cursor
  __shared__ int gbase[NBINS];   // global base per (bin, chunk)
  __shared__ int s[256];
  __shared__ int bsc[256];       // exclusive scan of bsum (98 valid)
  int t  = threadIdx.x;
  int ch = blockIdx.x;

  // bsum exclusive scan (folded k_hscan2)
  s[t] = (t < HS_BLOCKS) ? bsum[t] : 0;
  __syncthreads();
  #pragma unroll
  for (int off = 1; off < 256; off <<= 1) {
    int xv = (t >= off) ? s[t - off] : 0;
    __syncthreads();
    s[t] += xv;
    __syncthreads();
  }
  bsc[t] = (t > 0) ? s[t - 1] : 0;
  __syncthreads();

  {
    int i0 = t * NB1 + ch;
    int i1 = (t + 256) * NB1 + ch;
    gbase[t]       = bh[i0] + bsc[i0 >> 10];
    gbase[t + 256] = bh[i1] + bsc[i1 >> 10];
  }
  hist[t] = 0; hist[t + 256] = 0;
  __syncthreads();

  const int4* s4p = (const int4*)ei;
  const int4* d4p = (const int4*)(ei + E_EDGES);

  // pass 1: count
  #pragma unroll
  for (int u = 0; u < 8; ++u) {
    int i4 = ch * (CHUNK / 4) + u * 256 + t;
    if (i4 < E_EDGES / 4) {
      int4 d = d4p[i4];
      atomicAdd(&hist[d.x >> 8], 1);
      atomicAdd(&hist[d.y >> 8], 1);
      atomicAdd(&hist[d.z >> 8], 1);
      atomicAdd(&hist[d.w >> 8], 1);
    }
  }
  __syncthreads();

  // scan 512 bins via 256 pair-partials
  int h0 = hist[2 * t], h1 = hist[2 * t + 1];
  s[t] = h0 + h1;
  __syncthreads();
  #pragma unroll
  for (int off = 1; off < 256; off <<= 1) {
    int xv = (t >= off) ? s[t - off] : 0;
    __syncthreads();
    s[t] += xv;
    __syncthreads();
  }
  int ex = (t > 0) ? s[t - 1] : 0;
  ebase[2 * t] = ex;
  ebase[2 * t + 1] = ex + h0;
  cur[2 * t] = ex;
  cur[2 * t + 1] = ex + h0;
  __syncthreads();

  // pass 2: place edges bin-sorted into LDS, record final global address
  #pragma unroll
  for (int u = 0; u < 8; ++u) {
    int i4 = ch * (CHUNK / 4) + u * 256 + t;
    if (i4 < E_EDGES / 4) {
      int4 sv = s4p[i4];
      int4 dv = d4p[i4];
      {
        int bin = dv.x >> 8; int pos = atomicAdd(&cur[bin], 1);
        stage[pos] = sv.x | ((dv.x & 255) << 20);
        addr[pos]  = gbase[bin] + (pos - ebase[bin]);
      }
      {
        int bin = dv.y >> 8; int pos = atomicAdd(&cur[bin], 1);
        stage[pos] = sv.y | ((dv.y & 255) << 20);
        addr[pos]  = gbase[bin] + (pos - ebase[bin]);
      }
      {
        int bin = dv.z >> 8; int pos = atomicAdd(&cur[bin], 1);
        stage[pos] = sv.z | ((dv.z & 255) << 20);
        addr[pos]  = gbase[bin] + (pos - ebase[bin]);
      }
      {
        int bin = dv.w >> 8; int pos = atomicAdd(&cur[bin], 1);
        stage[pos] = sv.w | ((dv.w & 255) << 20);
        addr[pos]  = gbase[bin] + (pos - ebase[bin]);
      }
    }
  }
  __syncthreads();

  // write-out: mostly-consecutive addresses (contiguous runs per bin)
  int cbase = ch * CHUNK;
  int cnt = E_EDGES - cbase;
  if (cnt > CHUNK) cnt = CHUNK;
  for (int i = t; i < cnt; i += 256)
    binned[addr[i]] = stage[i];
}

// ---------------- level-2: per-bucket exact CSR (one block per bucket) -------
__global__ __launch_bounds__(256) void k_csr(const int* __restrict__ bh,
                                             const int* __restrict__ bsum,
                                             const int* __restrict__ binned,
                                             int* __restrict__ offs,
                                             int* __restrict__ srcidx) {
  __shared__ int h[256];
  __shared__ int s[256];
  __shared__ int cur[256];
  __shared__ int bsc[256];
  int t = threadIdx.x;
  int bin = blockIdx.x;

  // bsum exclusive scan (folded k_hscan2)
  s[t] = (t < HS_BLOCKS) ? bsum[t] : 0;
  __syncthreads();
  #pragma unroll
  for (int off = 1; off < 256; off <<= 1) {
    int xv = (t >= off) ? s[t - off] : 0;
    __syncthreads();
    s[t] += xv;
    __syncthreads();
  }
  bsc[t] = (t > 0) ? s[t - 1] : 0;
  __syncthreads();

  int i0 = bin * NB1, i1 = (bin + 1) * NB1;
  int base = bh[i0] + bsc[i0 >> 10];
  int end  = bh[i1] + bsc[i1 >> 10];

  h[t] = 0;
  __syncthreads();
  for (int i = base + t; i < end; i += 256)
    atomicAdd(&h[(binned[i] >> 20) & 255], 1);
  __syncthreads();
  s[t] = h[t];
  __syncthreads();
  #pragma unroll
  for (int off = 1; off < 256; off <<= 1) {
    int x = (t >= off) ? s[t - off] : 0;
    __syncthreads();
    s[t] += x;
    __syncthreads();
  }
  int excl = (t > 0) ? s[t - 1] : 0;
  cur[t] = excl;
  int node = bin * 256 + t;
  if (node < N_NODES) offs[node] = base + excl;
  if (node == N_NODES) offs[N_NODES] = E_EDGES;
  __syncthreads();
  for (int i = base + t; i < end; i += 256) {
    int p = binned[i];
    int r = atomicAdd(&cur[(p >> 20) & 255], 1);
    srcidx[base + r] = p & 0xFFFFF;
  }
}

// -------- fused gather+mean+GEMM, WAVE-DECOUPLED (no __syncthreads) ----------
// Each wave owns 16 rows: gathers 8 pairs (16-outstanding interleave) into its
// PRIVATE LDS slice, then runs its own 16x128 GEMM (64 MFMAs). No inter-wave
// barrier -> no max-of-8-waves imbalance tax; GEMM of one wave overlaps the
// gather of others.
__global__ __launch_bounds__(256) void k_gathgemm(const unsigned* __restrict__ hb,
                                                  const int* __restrict__ offs,
                                                  const int* __restrict__ srcidx,
                                                  const unsigned* __restrict__ wtb,
                                                  const float* __restrict__ bl,
                                                  float* __restrict__ out) {
  __shared__ unsigned agg[4][16 * 68];  // per-wave slice; stride 68 (2-way alias only)
  int wv   = threadIdx.x >> 6;
  int lane = threadIdx.x & 63;
  unsigned* ag = agg[wv];
  int r0w = (blockIdx.x * 4 + wv) * 16;

  for (int p = 0; p < 8; ++p) {
    int n0 = r0w + 2 * p;
    int n1 = n0 + 1;
    int c0 = (n0 < N_NODES) ? n0 : N_NODES;
    int c1 = (n0 + 1 < N_NODES) ? n0 + 1 : N_NODES;
    int c2 = (n1 + 1 < N_NODES) ? n1 + 1 : N_NODES;
    int b0 = __builtin_amdgcn_readfirstlane(offs[c0]);
    int e0 = __builtin_amdgcn_readfirstlane(offs[c1]);
    int b1 = e0;
    int e1 = __builtin_amdgcn_readfirstlane(offs[c2]);
    if (n1 > N_NODES) { b1 = e1 = b0; }   // fully out of range -> empty
    int m0 = e0 - b0, m1 = e1 - b1;
    int c  = (m0 < m1 ? m0 : m1) & ~7;

    float ax0 = 0.0f, ay0 = 0.0f, ax1 = 0.0f, ay1 = 0.0f;

    for (int j = 0; j < c; j += 8) {
      unsigned p0[8], p1[8];
      #pragma unroll
      for (int i = 0; i < 8; ++i) {
        int s0 = srcidx[b0 + j + i];
        int s1 = srcidx[b1 + j + i];
        p0[i] = hb[(size_t)s0 * 64 + lane];
        p1[i] = hb[(size_t)s1 * 64 + lane];
      }
      #pragma unroll
      for (int i = 0; i < 8; ++i) {
        float2 v0 = bf16unpack(p0[i]);
        float2 v1 = bf16unpack(p1[i]);
        ax0 += v0.x; ay0 += v0.y;
        ax1 += v1.x; ay1 += v1.y;
      }
    }
    for (int j = b0 + c; j < e0; ) {
      int rem = e0 - j;
      if (rem >= 8) {
        unsigned pp[8];
        #pragma unroll
        for (int i = 0; i < 8; ++i) pp[i] = hb[(size_t)srcidx[j + i] * 64 + lane];
        #pragma unroll
        for (int i = 0; i < 8; ++i) { float2 v = bf16unpack(pp[i]); ax0 += v.x; ay0 += v.y; }
        j += 8;
      } else {
        float2 v = bf16unpack(hb[(size_t)srcidx[j] * 64 + lane]);
        ax0 += v.x; ay0 += v.y;
        ++j;
      }
    }
    for (int j = b1 + c; j < e1; ) {
      int rem = e1 - j;
      if (rem >= 8) {
        unsigned pp[8];
        #pragma unroll
        for (int i = 0; i < 8; ++i) pp[i] = hb[(size_t)srcidx[j + i] * 64 + lane];
        #pragma unroll
        for (int i = 0; i < 8; ++i) { float2 v = bf16unpack(pp[i]); ax1 += v.x; ay1 += v.y; }
        j += 8;
      } else {
        float2 v = bf16unpack(hb[(size_t)srcidx[j] * 64 + lane]);
        ax1 += v.x; ay1 += v.y;
        ++j;
      }
    }

    float inv0 = 1.0f / fmaxf((float)m0, 1.0f);
    float inv1 = 1.0f / fmaxf((float)m1, 1.0f);
    ag[(2 * p + 0) * 68 + lane] = bf16pack(ax0 * inv0, ay0 * inv0);
    ag[(2 * p + 1) * 68 + lane] = bf16pack(ax1 * inv1, ay1 * inv1);
  }
  // no barrier: same-wave ds_write -> ds_read ordered via lgkmcnt

  // ---- per-wave GEMM: 16 rows x 128 cols over K=256 ([agg | h]) ----
  int m = lane & 15;
  int q = lane >> 4;
  int rowA = r0w + m;
  if (rowA > N_NODES - 1) rowA = N_NODES - 1;

  short8 afrag[8];
  #pragma unroll
  for (int kb = 0; kb < 4; ++kb) {             // K 0..127 from agg (wave LDS)
    uint4 u = *(const uint4*)&ag[m * 68 + (kb * 4 + q) * 4];
    afrag[kb] = *(short8*)&u;
  }
  const uint4* hr = (const uint4*)(hb + (size_t)rowA * 64);
  #pragma unroll
  for (int kb = 0; kb < 4; ++kb) {             // K 128..255 from h (global)
    uint4 u = hr[kb * 4 + q];
    afrag[kb + 4] = *(short8*)&u;
  }

  const uint4* b4 = (const uint4*)wtb;
  #pragma unroll
  for (int ct = 0; ct < 8; ++ct) {
    int col = ct * 16 + m;
    floatx4 acc = {0.0f, 0.0f, 0.0f, 0.0f};
    #pragma unroll
    for (int kb = 0; kb < 8; ++kb) {
      uint4 u = b4[kb * 512 + col * 4 + q];
      short8 bfrag = *(short8*)&u;
      acc = __builtin_amdgcn_mfma_f32_16x16x32_bf16(afrag[kb], bfrag, acc, 0, 0, 0);
    }
    float bias = bl[col];
    #pragma unroll
    for (int reg = 0; reg < 4; ++reg) {
      int r = r0w + q * 4 + reg;
      if (r < N_NODES) out[(size_t)r * DIM + col] = acc[reg] + bias;
    }
  }
}

extern "C" void kernel_launch(void* const* d_in, const int* in_sizes, int n_in,
                              void* d_out, int out_size, void* d_ws, size_t ws_size,
                              hipStream_t stream) {
  const float* x  = (const float*)d_in[0];
  const int*   ei = (const int*)d_in[1];   // [2, E] int32
  const float* lw = (const float*)d_in[2];
  const float* lb = (const float*)d_in[3];
  const float* Wl = (const float*)d_in[4];
  const float* bl = (const float*)d_in[5];
  const float* Wr = (const float*)d_in[6];
  float* out = (float*)d_out;

  char* ws = (char*)d_ws;
  unsigned* hb     = (unsigned*)(ws + HB_OFF);
  unsigned* wtb    = (unsigned*)(ws + WTB_OFF);
  int*      offs   = (int*)(ws + OFFS_OFF);
  int*      bh     = (int*)(ws + BH_OFF);
  int*      bsum   = (int*)(ws + BSUM_OFF);
  int*      binned = (int*)(ws + BIN_OFF);
  int*      srcidx = (int*)(ws + SRC_OFF);

  k_prep<<<N_NODES / 4, 256, 0, stream>>>(x, lw, lb, Wl, Wr, ei, hb, wtb, bh);
  k_hscan1<<<HS_BLOCKS, 256, 0, stream>>>(bh, bsum);
  k_binsort<<<NB1, 256, 0, stream>>>(ei, bh, bsum, binned);
  k_csr<<<NBUCKET, 256, 0, stream>>>(bh, bsum, binned, offs, srcidx);
  k_gathgemm<<<(N_NODES + 63) / 64, 256, 0, stream>>>(hb, offs, srcidx, wtb, bl, out);
}

// Round 8
// 255.482 us; speedup vs baseline: 1.1192x; 1.1192x over previous
//
#include <hip/hip_runtime.h>

#define N_NODES 100000
#define E_EDGES 1600000
#define DIM     128

// Binning geometry:
//  coarse bucket = 256 nodes (dst>>8): 391 real buckets, padded 512
//  chunk = 8192 edges: 196 chunks
#define NB1     196            // level-1 chunks (8192 edges each)
#define CHUNK   8192
#define NBINS   512            // padded bucket count (actual 391)
#define NBUCKET 391
#define NBH     (NBINS * NB1)  // 100352 bin-major [bin][chunk] histogram entries
#define HS_BLOCKS 98           // NBH / 1024 exactly

// Workspace layout (bytes), total ~64.9 MiB:
#define HB_OFF    0            // h packed bf16: N*64 u32 = 25,600,000
#define WTB_OFF   25600000     // WcatT bf16 B-fragment layout: 16384 u32 = 65,536
#define OFFS_OFF  25665536     // N+1 int (padded to 400,064)
#define BH_OFF    26065600     // NBH ints = 401,408
#define BSUM_OFF  26467008     // 98 ints (padded to 1024)
#define BIN_OFF   26468032     // E ints = 6,400,000
#define SRC_OFF   32868032     // E ints = 6,400,000
#define AGGB_OFF  39268032     // N*64 u32 = 25,600,000 -> end 64,868,032

typedef __attribute__((ext_vector_type(8))) short short8;
typedef __attribute__((ext_vector_type(4))) float floatx4;

// ---------- bf16 pack/unpack (RNE) ----------
__device__ __forceinline__ unsigned bf16pack(float a, float b) {
  unsigned ua = __float_as_uint(a); ua += 0x7fffu + ((ua >> 16) & 1u);
  unsigned ub = __float_as_uint(b); ub += 0x7fffu + ((ub >> 16) & 1u);
  return (ua >> 16) | (ub & 0xffff0000u);
}
__device__ __forceinline__ float2 bf16unpack(unsigned p) {
  return make_float2(__uint_as_float(p << 16), __uint_as_float(p & 0xffff0000u));
}

// ------------- prep: LayerNorm+ReLU -> hb, weight pack, level-1 histogram ----
__global__ __launch_bounds__(256) void k_prep(const float* __restrict__ x,
                                              const float* __restrict__ lw,
                                              const float* __restrict__ lb,
                                              const float* __restrict__ Wl,
                                              const float* __restrict__ Wr,
                                              const int* __restrict__ ei,
                                              unsigned* __restrict__ hb,
                                              unsigned* __restrict__ wtb,
                                              int* __restrict__ bh) {
  int gid = blockIdx.x * 256 + threadIdx.x;
  int t = threadIdx.x;

  // --- LN+ReLU ---
  {
    int row  = blockIdx.x * 4 + (t >> 6);
    int lane = t & 63;
    float2 v = ((const float2*)(x + (size_t)row * DIM))[lane];
    float s  = v.x + v.y;
    float sq = v.x * v.x + v.y * v.y;
    #pragma unroll
    for (int off = 32; off > 0; off >>= 1) {
      s  += __shfl_xor(s, off);
      sq += __shfl_xor(sq, off);
    }
    float mu  = s * (1.0f / 128.0f);
    float var = sq * (1.0f / 128.0f) - mu * mu;
    float rs  = rsqrtf(var + 1e-5f);
    float2 w = ((const float2*)lw)[lane];
    float2 b = ((const float2*)lb)[lane];
    float ox = fmaxf((v.x - mu) * rs * w.x + b.x, 0.0f);
    float oy = fmaxf((v.y - mu) * rs * w.y + b.y, 0.0f);
    hb[(size_t)row * 64 + lane] = bf16pack(ox, oy);
  }

  // --- weight pack (bf16, B-fragment layout) ---
  if (gid < 16384) {
    int j2 = gid & 3;
    int q  = (gid >> 2) & 3;
    int c  = (gid >> 4) & 127;
    int kb = gid >> 11;
    int k0 = kb * 32 + q * 8 + j2 * 2;
    int k1 = k0 + 1;
    float v0 = (k0 < 128) ? Wl[c * 128 + k0] : Wr[c * 128 + (k0 - 128)];
    float v1 = (k1 < 128) ? Wl[c * 128 + k1] : Wr[c * 128 + (k1 - 128)];
    wtb[gid] = bf16pack(v0, v1);
  }

  // --- level-1 histogram: chunk = 8192 edges (block-uniform branch) ---
  if (blockIdx.x < NB1) {
    __shared__ int h[NBINS];
    h[t] = 0; h[t + 256] = 0;
    __syncthreads();
    const int4* d4p = (const int4*)(ei + E_EDGES);
    #pragma unroll
    for (int u = 0; u < 8; ++u) {
      int i4 = blockIdx.x * (CHUNK / 4) + u * 256 + t;
      if (i4 < E_EDGES / 4) {
        int4 d = d4p[i4];
        atomicAdd(&h[d.x >> 8], 1);
        atomicAdd(&h[d.y >> 8], 1);
        atomicAdd(&h[d.z >> 8], 1);
        atomicAdd(&h[d.w >> 8], 1);
      }
    }
    __syncthreads();
    bh[t * NB1 + blockIdx.x] = h[t];
    bh[(t + 256) * NB1 + blockIdx.x] = h[t + 256];
  }
}

// ---------------- scan stage 1 over bh (in-place, 1024 elems/block) ----------
// Leaves bh as block-local exclusive scans; bsum holds the 98 block totals.
// (Stage-2 base-add is folded into binsort/csr via an LDS bsum scan.)
__global__ __launch_bounds__(256) void k_hscan1(int* __restrict__ bh,
                                                int* __restrict__ bsum) {
  __shared__ int s[256];
  int t = threadIdx.x;
  int base = blockIdx.x * 1024 + t * 4;
  int a0 = (base + 0 < NBH) ? bh[base + 0] : 0;
  int a1 = (base + 1 < NBH) ? bh[base + 1] : 0;
  int a2 = (base + 2 < NBH) ? bh[base + 2] : 0;
  int a3 = (base + 3 < NBH) ? bh[base + 3] : 0;
  s[t] = a0 + a1 + a2 + a3;
  __syncthreads();
  #pragma unroll
  for (int off = 1; off < 256; off <<= 1) {
    int x = (t >= off) ? s[t - off] : 0;
    __syncthreads();
    s[t] += x;
    __syncthreads();
  }
  int excl = (t > 0) ? s[t - 1] : 0;
  if (t == 255) bsum[blockIdx.x] = s[255];
  if (base + 0 < NBH) bh[base + 0] = excl;
  if (base + 1 < NBH) bh[base + 1] = excl + a0;
  if (base + 2 < NBH) bh[base + 2] = excl + a0 + a1;
  if (base + 3 < NBH) bh[base + 3] = excl + a0 + a1 + a2;
}

// ------- level-1 bin-sort: LDS-sorted chunk, COALESCED write-out -------------
__global__ __launch_bounds__(256) void k_binsort(const int* __restrict__ ei,
                                                 const int* __restrict__ bh,
                                                 const int* __restrict__ bsum,
                                                 int* __restrict__ binned) {
  __shared__ int stage[CHUNK];   // 32 KiB: bin-sorted packed edges
  __shared__ int addr[CHUNK];    // 32 KiB: final global index per staged edge
  __shared__ int hist[NBINS];
  __shared__ int ebase[NBINS];   // intra-chunk exclusive base per bin
  __shared__ int cur[NBINS];     // placement cursor
  __shared__ int gbase[NBINS];   // global base per (bin, chunk)
  __shared__ int s[256];
  __shared__ int bsc[256];       // exclusive scan of bsum (98 valid)
  int t  = threadIdx.x;
  int ch = blockIdx.x;

  // bsum exclusive scan (folded k_hscan2)
  s[t] = (t < HS_BLOCKS) ? bsum[t] : 0;
  __syncthreads();
  #pragma unroll
  for (int off = 1; off < 256; off <<= 1) {
    int xv = (t >= off) ? s[t - off] : 0;
    __syncthreads();
    s[t] += xv;
    __syncthreads();
  }
  bsc[t] = (t > 0) ? s[t - 1] : 0;
  __syncthreads();

  {
    int i0 = t * NB1 + ch;
    int i1 = (t + 256) * NB1 + ch;
    gbase[t]       = bh[i0] + bsc[i0 >> 10];
    gbase[t + 256] = bh[i1] + bsc[i1 >> 10];
  }
  hist[t] = 0; hist[t + 256] = 0;
  __syncthreads();

  const int4* s4p = (const int4*)ei;
  const int4* d4p = (const int4*)(ei + E_EDGES);

  // pass 1: count
  #pragma unroll
  for (int u = 0; u < 8; ++u) {
    int i4 = ch * (CHUNK / 4) + u * 256 + t;
    if (i4 < E_EDGES / 4) {
      int4 d = d4p[i4];
      atomicAdd(&hist[d.x >> 8], 1);
      atomicAdd(&hist[d.y >> 8], 1);
      atomicAdd(&hist[d.z >> 8], 1);
      atomicAdd(&hist[d.w >> 8], 1);
    }
  }
  __syncthreads();

  // scan 512 bins via 256 pair-partials
  int h0 = hist[2 * t], h1 = hist[2 * t + 1];
  s[t] = h0 + h1;
  __syncthreads();
  #pragma unroll
  for (int off = 1; off < 256; off <<= 1) {
    int xv = (t >= off) ? s[t - off] : 0;
    __syncthreads();
    s[t] += xv;
    __syncthreads();
  }
  int ex = (t > 0) ? s[t - 1] : 0;
  ebase[2 * t] = ex;
  ebase[2 * t + 1] = ex + h0;
  cur[2 * t] = ex;
  cur[2 * t + 1] = ex + h0;
  __syncthreads();

  // pass 2: place edges bin-sorted into LDS, record final global address
  #pragma unroll
  for (int u = 0; u < 8; ++u) {
    int i4 = ch * (CHUNK / 4) + u * 256 + t;
    if (i4 < E_EDGES / 4) {
      int4 sv = s4p[i4];
      int4 dv = d4p[i4];
      {
        int bin = dv.x >> 8; int pos = atomicAdd(&cur[bin], 1);
        stage[pos] = sv.x | ((dv.x & 255) << 20);
        addr[pos]  = gbase[bin] + (pos - ebase[bin]);
      }
      {
        int bin = dv.y >> 8; int pos = atomicAdd(&cur[bin], 1);
        stage[pos] = sv.y | ((dv.y & 255) << 20);
        addr[pos]  = gbase[bin] + (pos - ebase[bin]);
      }
      {
        int bin = dv.z >> 8; int pos = atomicAdd(&cur[bin], 1);
        stage[pos] = sv.z | ((dv.z & 255) << 20);
        addr[pos]  = gbase[bin] + (pos - ebase[bin]);
      }
      {
        int bin = dv.w >> 8; int pos = atomicAdd(&cur[bin], 1);
        stage[pos] = sv.w | ((dv.w & 255) << 20);
        addr[pos]  = gbase[bin] + (pos - ebase[bin]);
      }
    }
  }
  __syncthreads();

  // write-out: mostly-consecutive addresses (contiguous runs per bin)
  int cbase = ch * CHUNK;
  int cnt = E_EDGES - cbase;
  if (cnt > CHUNK) cnt = CHUNK;
  for (int i = t; i < cnt; i += 256)
    binned[addr[i]] = stage[i];
}

// ---------------- level-2: per-bucket exact CSR (one block per bucket) -------
__global__ __launch_bounds__(256) void k_csr(const int* __restrict__ bh,
                                             const int* __restrict__ bsum,
                                             const int* __restrict__ binned,
                                             int* __restrict__ offs,
                                             int* __restrict__ srcidx) {
  __shared__ int h[256];
  __shared__ int s[256];
  __shared__ int cur[256];
  __shared__ int bsc[256];
  int t = threadIdx.x;
  int bin = blockIdx.x;

  // bsum exclusive scan (folded k_hscan2)
  s[t] = (t < HS_BLOCKS) ? bsum[t] : 0;
  __syncthreads();
  #pragma unroll
  for (int off = 1; off < 256; off <<= 1) {
    int xv = (t >= off) ? s[t - off] : 0;
    __syncthreads();
    s[t] += xv;
    __syncthreads();
  }
  bsc[t] = (t > 0) ? s[t - 1] : 0;
  __syncthreads();

  int i0 = bin * NB1, i1 = (bin + 1) * NB1;
  int base = bh[i0] + bsc[i0 >> 10];
  int end  = bh[i1] + bsc[i1 >> 10];

  h[t] = 0;
  __syncthreads();
  for (int i = base + t; i < end; i += 256)
    atomicAdd(&h[(binned[i] >> 20) & 255], 1);
  __syncthreads();
  s[t] = h[t];
  __syncthreads();
  #pragma unroll
  for (int off = 1; off < 256; off <<= 1) {
    int x = (t >= off) ? s[t - off] : 0;
    __syncthreads();
    s[t] += x;
    __syncthreads();
  }
  int excl = (t > 0) ? s[t - 1] : 0;
  cur[t] = excl;
  int node = bin * 256 + t;
  if (node < N_NODES) offs[node] = base + excl;
  if (node == N_NODES) offs[N_NODES] = E_EDGES;
  __syncthreads();
  for (int i = base + t; i < end; i += 256) {
    int p = binned[i];
    int r = atomicAdd(&cur[(p >> 20) & 255], 1);
    srcidx[base + r] = p & 0xFFFFF;
  }
}

// ---------------- gather + mean -> aggb (bf16): R2-proven, 50K waves ---------
__global__ __launch_bounds__(256) void k_gather(const unsigned* __restrict__ hb,
                                                const int* __restrict__ offs,
                                                const int* __restrict__ srcidx,
                                                unsigned* __restrict__ aggb) {
  int wave = threadIdx.x >> 6;
  int lane = threadIdx.x & 63;
  int n0 = blockIdx.x * 8 + wave * 2;
  int n1 = n0 + 1;
  int b0 = __builtin_amdgcn_readfirstlane(offs[n0]);
  int e0 = __builtin_amdgcn_readfirstlane(offs[n0 + 1]);
  int b1 = __builtin_amdgcn_readfirstlane(offs[n1]);
  int e1 = __builtin_amdgcn_readfirstlane(offs[n1 + 1]);
  int m0 = e0 - b0, m1 = e1 - b1;
  int c  = (m0 < m1 ? m0 : m1) & ~7;   // common interleaved part

  float ax0 = 0.0f, ay0 = 0.0f, ax1 = 0.0f, ay1 = 0.0f;

  // interleaved: 16 outstanding loads (8 per chain)
  for (int j = 0; j < c; j += 8) {
    unsigned p0[8], p1[8];
    #pragma unroll
    for (int i = 0; i < 8; ++i) {
      int s0 = srcidx[b0 + j + i];
      int s1 = srcidx[b1 + j + i];
      p0[i] = hb[(size_t)s0 * 64 + lane];
      p1[i] = hb[(size_t)s1 * 64 + lane];
    }
    #pragma unroll
    for (int i = 0; i < 8; ++i) {
      float2 v0 = bf16unpack(p0[i]);
      float2 v1 = bf16unpack(p1[i]);
      ax0 += v0.x; ay0 += v0.y;
      ax1 += v1.x; ay1 += v1.y;
    }
  }
  for (int j = b0 + c; j < e0; ) {
    int rem = e0 - j;
    if (rem >= 8) {
      unsigned p[8];
      #pragma unroll
      for (int i = 0; i < 8; ++i) p[i] = hb[(size_t)srcidx[j + i] * 64 + lane];
      #pragma unroll
      for (int i = 0; i < 8; ++i) { float2 v = bf16unpack(p[i]); ax0 += v.x; ay0 += v.y; }
      j += 8;
    } else {
      float2 v = bf16unpack(hb[(size_t)srcidx[j] * 64 + lane]);
      ax0 += v.x; ay0 += v.y;
      ++j;
    }
  }
  for (int j = b1 + c; j < e1; ) {
    int rem = e1 - j;
    if (rem >= 8) {
      unsigned p[8];
      #pragma unroll
      for (int i = 0; i < 8; ++i) p[i] = hb[(size_t)srcidx[j + i] * 64 + lane];
      #pragma unroll
      for (int i = 0; i < 8; ++i) { float2 v = bf16unpack(p[i]); ax1 += v.x; ay1 += v.y; }
      j += 8;
    } else {
      float2 v = bf16unpack(hb[(size_t)srcidx[j] * 64 + lane]);
      ax1 += v.x; ay1 += v.y;
      ++j;
    }
  }

  float inv0 = 1.0f / fmaxf((float)m0, 1.0f);
  float inv1 = 1.0f / fmaxf((float)m1, 1.0f);
  aggb[(size_t)n0 * 64 + lane] = bf16pack(ax0 * inv0, ay0 * inv0);
  aggb[(size_t)n1 * 64 + lane] = bf16pack(ax1 * inv1, ay1 * inv1);
}

// ---------------- bf16 MFMA GEMM: out = [aggb|hb] @ WcatT^T + b_l ------------
__global__ __launch_bounds__(256) void k_gemm(const unsigned* __restrict__ aggb,
                                              const unsigned* __restrict__ hb,
                                              const unsigned* __restrict__ wtb,
                                              const float* __restrict__ bl,
                                              float* __restrict__ out) {
  int wave = threadIdx.x >> 6;
  int lane = threadIdx.x & 63;
  int m = lane & 15;
  int q = lane >> 4;
  int r0 = blockIdx.x * 64 + wave * 16;
  int rowA = r0 + m;
  if (rowA > N_NODES - 1) rowA = N_NODES - 1;  // tail clamp (stores guarded)

  const uint4* ar = (const uint4*)(aggb + (size_t)rowA * 64);
  const uint4* hr = (const uint4*)(hb + (size_t)rowA * 64);
  short8 afrag[8];
  #pragma unroll
  for (int kb = 0; kb < 4; ++kb) {
    uint4 u = ar[kb * 4 + q];
    afrag[kb] = *(short8*)&u;
  }
  #pragma unroll
  for (int kb = 0; kb < 4; ++kb) {
    uint4 u = hr[kb * 4 + q];
    afrag[kb + 4] = *(short8*)&u;
  }

  const uint4* b4 = (const uint4*)wtb;
  #pragma unroll
  for (int ct = 0; ct < 8; ++ct) {
    int c = ct * 16 + m;
    floatx4 acc = {0.0f, 0.0f, 0.0f, 0.0f};
    #pragma unroll
    for (int kb = 0; kb < 8; ++kb) {
      uint4 u = b4[kb * 512 + c * 4 + q];
      short8 bfrag = *(short8*)&u;
      acc = __builtin_amdgcn_mfma_f32_16x16x32_bf16(afrag[kb], bfrag, acc, 0, 0, 0);
    }
    float bias = bl[c];
    #pragma unroll
    for (int reg = 0; reg < 4; ++reg) {
      int r = r0 + q * 4 + reg;
      if (r < N_NODES) out[(size_t)r * DIM + c] = acc[reg] + bias;
    }
  }
}

extern "C" void kernel_launch(void* const* d_in, const int* in_sizes, int n_in,
                              void* d_out, int out_size, void* d_ws, size_t ws_size,
                              hipStream_t stream) {
  const float* x  = (const float*)d_in[0];
  const int*   ei = (const int*)d_in[1];   // [2, E] int32
  const float* lw = (const float*)d_in[2];
  const float* lb = (const float*)d_in[3];
  const float* Wl = (const float*)d_in[4];
  const float* bl = (const float*)d_in[5];
  const float* Wr = (const float*)d_in[6];
  float* out = (float*)d_out;

  char* ws = (char*)d_ws;
  unsigned* hb     = (unsigned*)(ws + HB_OFF);
  unsigned* wtb    = (unsigned*)(ws + WTB_OFF);
  int*      offs   = (int*)(ws + OFFS_OFF);
  int*      bh     = (int*)(ws + BH_OFF);
  int*      bsum   = (int*)(ws + BSUM_OFF);
  int*      binned = (int*)(ws + BIN_OFF);
  int*      srcidx = (int*)(ws + SRC_OFF);
  unsigned* aggb   = (unsigned*)(ws + AGGB_OFF);

  k_prep<<<N_NODES / 4, 256, 0, stream>>>(x, lw, lb, Wl, Wr, ei, hb, wtb, bh);
  k_hscan1<<<HS_BLOCKS, 256, 0, stream>>>(bh, bsum);
  k_binsort<<<NB1, 256, 0, stream>>>(ei, bh, bsum, binned);
  k_csr<<<NBUCKET, 256, 0, stream>>>(bh, bsum, binned, offs, srcidx);
  k_gather<<<N_NODES / 8, 256, 0, stream>>>(hb, offs, srcidx, aggb);
  k_gemm<<<(N_NODES + 63) / 64, 256, 0, stream>>>(aggb, hb, wtb, bl, out);
}

// Round 10
// 251.752 us; speedup vs baseline: 1.1358x; 1.0148x over previous
//
#include <hip/hip_runtime.h>

#define N_NODES 100000
#define E_EDGES 1600000
#define DIM     128

// Binning geometry:
//  coarse bucket = 256 nodes (dst>>8): 391 real buckets, padded 512
//  chunk = 4096 edges: 391 chunks (matches prep-hist blocks; pass1 reuse)
#define NB1     391            // level-1 chunks (4096 edges each)
#define CHUNK   4096
#define NBINS   512            // padded bucket count (actual 391)
#define NBUCKET 391
#define NBH     (NBINS * NB1)  // 200192 bin-major [bin][chunk] histogram entries
#define HS_BLOCKS 196          // ceil(NBH/1024)

// Workspace layout (bytes), total ~66.1 MiB (<= 70.9 MiB proven OK in R1):
#define HB_OFF    0            // h packed bf16: N*64 u32 = 25,600,000
#define WTB_OFF   25600000     // WcatT bf16 B-fragment layout: 16384 u32 = 65,536
#define OFFS_OFF  25665536     // N+1 int (padded to 400,064)
#define BHC_OFF   26065600     // raw counts: NBH ints = 800,768 (pad 800,832)
#define BH_OFF    26866432     // scanned: NBH ints = 800,768
#define BSUM_OFF  27667200     // 196 ints (padded to 1024)
#define BIN_OFF   27668224     // E ints = 6,400,000
#define SRC_OFF   34068224     // E ints = 6,400,000
#define AGGB_OFF  40468224     // N*64 u32 = 25,600,000 -> end 66,068,224

typedef __attribute__((ext_vector_type(8))) short short8;
typedef __attribute__((ext_vector_type(4))) float floatx4;

// ---------- bf16 pack/unpack (RNE) ----------
__device__ __forceinline__ unsigned bf16pack(float a, float b) {
  unsigned ua = __float_as_uint(a); ua += 0x7fffu + ((ua >> 16) & 1u);
  unsigned ub = __float_as_uint(b); ub += 0x7fffu + ((ub >> 16) & 1u);
  return (ua >> 16) | (ub & 0xffff0000u);
}
__device__ __forceinline__ float2 bf16unpack(unsigned p) {
  return make_float2(__uint_as_float(p << 16), __uint_as_float(p & 0xffff0000u));
}

// ------------- prep: LayerNorm+ReLU -> hb, weight pack, level-1 histogram ----
__global__ __launch_bounds__(256) void k_prep(const float* __restrict__ x,
                                              const float* __restrict__ lw,
                                              const float* __restrict__ lb,
                                              const float* __restrict__ Wl,
                                              const float* __restrict__ Wr,
                                              const int* __restrict__ ei,
                                              unsigned* __restrict__ hb,
                                              unsigned* __restrict__ wtb,
                                              int* __restrict__ bhc) {
  int gid = blockIdx.x * 256 + threadIdx.x;
  int t = threadIdx.x;

  // --- LN+ReLU ---
  {
    int row  = blockIdx.x * 4 + (t >> 6);
    int lane = t & 63;
    float2 v = ((const float2*)(x + (size_t)row * DIM))[lane];
    float s  = v.x + v.y;
    float sq = v.x * v.x + v.y * v.y;
    #pragma unroll
    for (int off = 32; off > 0; off >>= 1) {
      s  += __shfl_xor(s, off);
      sq += __shfl_xor(sq, off);
    }
    float mu  = s * (1.0f / 128.0f);
    float var = sq * (1.0f / 128.0f) - mu * mu;
    float rs  = rsqrtf(var + 1e-5f);
    float2 w = ((const float2*)lw)[lane];
    float2 b = ((const float2*)lb)[lane];
    float ox = fmaxf((v.x - mu) * rs * w.x + b.x, 0.0f);
    float oy = fmaxf((v.y - mu) * rs * w.y + b.y, 0.0f);
    hb[(size_t)row * 64 + lane] = bf16pack(ox, oy);
  }

  // --- weight pack (bf16, B-fragment layout) ---
  if (gid < 16384) {
    int j2 = gid & 3;
    int q  = (gid >> 2) & 3;
    int c  = (gid >> 4) & 127;
    int kb = gid >> 11;
    int k0 = kb * 32 + q * 8 + j2 * 2;
    int k1 = k0 + 1;
    float v0 = (k0 < 128) ? Wl[c * 128 + k0] : Wr[c * 128 + (k0 - 128)];
    float v1 = (k1 < 128) ? Wl[c * 128 + k1] : Wr[c * 128 + (k1 - 128)];
    wtb[gid] = bf16pack(v0, v1);
  }

  // --- level-1 histogram: chunk = 4096 edges (block-uniform branch) ---
  // Counts saved to bhc (NOT overwritten by scan) so binsort reuses them.
  if (blockIdx.x < NB1) {
    __shared__ int h[NBINS];
    h[t] = 0; h[t + 256] = 0;
    __syncthreads();
    const int4* d4p = (const int4*)(ei + E_EDGES);
    #pragma unroll
    for (int u = 0; u < 4; ++u) {
      int i4 = blockIdx.x * (CHUNK / 4) + u * 256 + t;
      if (i4 < E_EDGES / 4) {
        int4 d = d4p[i4];
        atomicAdd(&h[d.x >> 8], 1);
        atomicAdd(&h[d.y >> 8], 1);
        atomicAdd(&h[d.z >> 8], 1);
        atomicAdd(&h[d.w >> 8], 1);
      }
    }
    __syncthreads();
    bhc[t * NB1 + blockIdx.x] = h[t];
    bhc[(t + 256) * NB1 + blockIdx.x] = h[t + 256];
  }
}

// ---------------- scan stage 1: bhc (counts) -> bh (block-local scans) -------
// bsum holds the 196 block totals; stage-2 base-add folded into consumers.
__global__ __launch_bounds__(256) void k_hscan1(const int* __restrict__ bhc,
                                                int* __restrict__ bh,
                                                int* __restrict__ bsum) {
  __shared__ int s[256];
  int t = threadIdx.x;
  int base = blockIdx.x * 1024 + t * 4;
  int a0 = (base + 0 < NBH) ? bhc[base + 0] : 0;
  int a1 = (base + 1 < NBH) ? bhc[base + 1] : 0;
  int a2 = (base + 2 < NBH) ? bhc[base + 2] : 0;
  int a3 = (base + 3 < NBH) ? bhc[base + 3] : 0;
  s[t] = a0 + a1 + a2 + a3;
  __syncthreads();
  #pragma unroll
  for (int off = 1; off < 256; off <<= 1) {
    int x = (t >= off) ? s[t - off] : 0;
    __syncthreads();
    s[t] += x;
    __syncthreads();
  }
  int excl = (t > 0) ? s[t - 1] : 0;
  if (t == 255) bsum[blockIdx.x] = s[255];
  if (base + 0 < NBH) bh[base + 0] = excl;
  if (base + 1 < NBH) bh[base + 1] = excl + a0;
  if (base + 2 < NBH) bh[base + 2] = excl + a0 + a1;
  if (base + 3 < NBH) bh[base + 3] = excl + a0 + a1 + a2;
}

// ------- level-1 bin-sort: reuses prep's histogram (NO pass-1 atomics) -------
// Loads chunk counts from bhc, LDS-scans them (no atomics), then places edges
// (pass2 atomic-with-return) and streams out coalesced.
__global__ __launch_bounds__(256) void k_binsort(const int* __restrict__ ei,
                                                 const int* __restrict__ bh,
                                                 const int* __restrict__ bhc,
                                                 const int* __restrict__ bsum,
                                                 int* __restrict__ binned) {
  __shared__ int stage[CHUNK];   // 16 KiB: bin-sorted packed edges
  __shared__ int addr[CHUNK];    // 16 KiB: final global index per staged edge
  __shared__ int hist[NBINS];    // chunk counts (loaded, not recomputed)
  __shared__ int ebase[NBINS];   // intra-chunk exclusive base per bin
  __shared__ int cur[NBINS];     // placement cursor
  __shared__ int gbase[NBINS];   // global base per (bin, chunk)
  __shared__ int s[256];
  __shared__ int bsc[256];       // exclusive scan of bsum (196 valid)
  int t  = threadIdx.x;
  int ch = blockIdx.x;

  // bsum exclusive scan (folded hscan2)
  s[t] = (t < HS_BLOCKS) ? bsum[t] : 0;
  __syncthreads();
  #pragma unroll
  for (int off = 1; off < 256; off <<= 1) {
    int xv = (t >= off) ? s[t - off] : 0;
    __syncthreads();
    s[t] += xv;
    __syncthreads();
  }
  bsc[t] = (t > 0) ? s[t - 1] : 0;
  __syncthreads();

  {
    int i0 = t * NB1 + ch;
    int i1 = (t + 256) * NB1 + ch;
    gbase[t]       = bh[i0] + bsc[i0 >> 10];
    gbase[t + 256] = bh[i1] + bsc[i1 >> 10];
    hist[t]        = bhc[i0];
    hist[t + 256]  = bhc[i1];
  }
  __syncthreads();

  // scan 512 bins via 256 pair-partials (no atomics)
  int h0 = hist[2 * t], h1 = hist[2 * t + 1];
  s[t] = h0 + h1;
  __syncthreads();
  #pragma unroll
  for (int off = 1; off < 256; off <<= 1) {
    int xv = (t >= off) ? s[t - off] : 0;
    __syncthreads();
    s[t] += xv;
    __syncthreads();
  }
  int ex = (t > 0) ? s[t - 1] : 0;
  ebase[2 * t] = ex;
  ebase[2 * t + 1] = ex + h0;
  cur[2 * t] = ex;
  cur[2 * t + 1] = ex + h0;
  __syncthreads();

  const int4* s4p = (const int4*)ei;
  const int4* d4p = (const int4*)(ei + E_EDGES);

  // place edges bin-sorted into LDS, record final global address
  #pragma unroll
  for (int u = 0; u < 4; ++u) {
    int i4 = ch * (CHUNK / 4) + u * 256 + t;
    if (i4 < E_EDGES / 4) {
      int4 sv = s4p[i4];
      int4 dv = d4p[i4];
      {
        int bin = dv.x >> 8; int pos = atomicAdd(&cur[bin], 1);
        stage[pos] = sv.x | ((dv.x & 255) << 20);
        addr[pos]  = gbase[bin] + (pos - ebase[bin]);
      }
      {
        int bin = dv.y >> 8; int pos = atomicAdd(&cur[bin], 1);
        stage[pos] = sv.y | ((dv.y & 255) << 20);
        addr[pos]  = gbase[bin] + (pos - ebase[bin]);
      }
      {
        int bin = dv.z >> 8; int pos = atomicAdd(&cur[bin], 1);
        stage[pos] = sv.z | ((dv.z & 255) << 20);
        addr[pos]  = gbase[bin] + (pos - ebase[bin]);
      }
      {
        int bin = dv.w >> 8; int pos = atomicAdd(&cur[bin], 1);
        stage[pos] = sv.w | ((dv.w & 255) << 20);
        addr[pos]  = gbase[bin] + (pos - ebase[bin]);
      }
    }
  }
  __syncthreads();

  // write-out: mostly-consecutive addresses (contiguous runs per bin)
  int cbase = ch * CHUNK;
  int cnt = E_EDGES - cbase;
  if (cnt > CHUNK) cnt = CHUNK;
  for (int i = t; i < cnt; i += 256)
    binned[addr[i]] = stage[i];
}

// ---------------- level-2: per-bucket exact CSR (one block per bucket) -------
__global__ __launch_bounds__(256) void k_csr(const int* __restrict__ bh,
                                             const int* __restrict__ bsum,
                                             const int* __restrict__ binned,
                                             int* __restrict__ offs,
                                             int* __restrict__ srcidx) {
  __shared__ int h[256];
  __shared__ int s[256];
  __shared__ int cur[256];
  __shared__ int bsc[256];
  int t = threadIdx.x;
  int bin = blockIdx.x;

  // bsum exclusive scan (folded hscan2)
  s[t] = (t < HS_BLOCKS) ? bsum[t] : 0;
  __syncthreads();
  #pragma unroll
  for (int off = 1; off < 256; off <<= 1) {
    int xv = (t >= off) ? s[t - off] : 0;
    __syncthreads();
    s[t] += xv;
    __syncthreads();
  }
  bsc[t] = (t > 0) ? s[t - 1] : 0;
  __syncthreads();

  int i0 = bin * NB1, i1 = (bin + 1) * NB1;
  int base = bh[i0] + bsc[i0 >> 10];
  int end  = (bin + 1 < NBINS) ? (bh[i1] + bsc[i1 >> 10]) : E_EDGES;

  h[t] = 0;
  __syncthreads();
  for (int i = base + t; i < end; i += 256)
    atomicAdd(&h[(binned[i] >> 20) & 255], 1);
  __syncthreads();
  s[t] = h[t];
  __syncthreads();
  #pragma unroll
  for (int off = 1; off < 256; off <<= 1) {
    int x = (t >= off) ? s[t - off] : 0;
    __syncthreads();
    s[t] += x;
    __syncthreads();
  }
  int excl = (t > 0) ? s[t - 1] : 0;
  cur[t] = excl;
  int node = bin * 256 + t;
  if (node < N_NODES) offs[node] = base + excl;
  if (node == N_NODES) offs[N_NODES] = E_EDGES;
  __syncthreads();
  for (int i = base + t; i < end; i += 256) {
    int p = binned[i];
    int r = atomicAdd(&cur[(p >> 20) & 255], 1);
    srcidx[base + r] = p & 0xFFFFF;
  }
}

// ---------------- gather + mean -> aggb (bf16): proven, 50K waves ------------
__global__ __launch_bounds__(256) void k_gather(const unsigned* __restrict__ hb,
                                                const int* __restrict__ offs,
                                                const int* __restrict__ srcidx,
                                                unsigned* __restrict__ aggb) {
  int wave = threadIdx.x >> 6;
  int lane = threadIdx.x & 63;
  int n0 = blockIdx.x * 8 + wave * 2;
  int n1 = n0 + 1;
  int b0 = __builtin_amdgcn_readfirstlane(offs[n0]);
  int e0 = __builtin_amdgcn_readfirstlane(offs[n0 + 1]);
  int b1 = __builtin_amdgcn_readfirstlane(offs[n1]);
  int e1 = __builtin_amdgcn_readfirstlane(offs[n1 + 1]);
  int m0 = e0 - b0, m1 = e1 - b1;
  int c  = (m0 < m1 ? m0 : m1) & ~7;   // common interleaved part

  float ax0 = 0.0f, ay0 = 0.0f, ax1 = 0.0f, ay1 = 0.0f;

  // interleaved: 16 outstanding loads (8 per chain)
  for (int j = 0; j < c; j += 8) {
    unsigned p0[8], p1[8];
    #pragma unroll
    for (int i = 0; i < 8; ++i) {
      int s0 = srcidx[b0 + j + i];
      int s1 = srcidx[b1 + j + i];
      p0[i] = hb[(size_t)s0 * 64 + lane];
      p1[i] = hb[(size_t)s1 * 64 + lane];
    }
    #pragma unroll
    for (int i = 0; i < 8; ++i) {
      float2 v0 = bf16unpack(p0[i]);
      float2 v1 = bf16unpack(p1[i]);
      ax0 += v0.x; ay0 += v0.y;
      ax1 += v1.x; ay1 += v1.y;
    }
  }
  for (int j = b0 + c; j < e0; ) {
    int rem = e0 - j;
    if (rem >= 8) {
      unsigned p[8];
      #pragma unroll
      for (int i = 0; i < 8; ++i) p[i] = hb[(size_t)srcidx[j + i] * 64 + lane];
      #pragma unroll
      for (int i = 0; i < 8; ++i) { float2 v = bf16unpack(p[i]); ax0 += v.x; ay0 += v.y; }
      j += 8;
    } else {
      float2 v = bf16unpack(hb[(size_t)srcidx[j] * 64 + lane]);
      ax0 += v.x; ay0 += v.y;
      ++j;
    }
  }
  for (int j = b1 + c; j < e1; ) {
    int rem = e1 - j;
    if (rem >= 8) {
      unsigned p[8];
      #pragma unroll
      for (int i = 0; i < 8; ++i) p[i] = hb[(size_t)srcidx[j + i] * 64 + lane];
      #pragma unroll
      for (int i = 0; i < 8; ++i) { float2 v = bf16unpack(p[i]); ax1 += v.x; ay1 += v.y; }
      j += 8;
    } else {
      float2 v = bf16unpack(hb[(size_t)srcidx[j] * 64 + lane]);
      ax1 += v.x; ay1 += v.y;
      ++j;
    }
  }

  float inv0 = 1.0f / fmaxf((float)m0, 1.0f);
  float inv1 = 1.0f / fmaxf((float)m1, 1.0f);
  aggb[(size_t)n0 * 64 + lane] = bf16pack(ax0 * inv0, ay0 * inv0);
  aggb[(size_t)n1 * 64 + lane] = bf16pack(ax1 * inv1, ay1 * inv1);
}

// ---------------- bf16 MFMA GEMM: out = [aggb|hb] @ WcatT^T + b_l ------------
__global__ __launch_bounds__(256) void k_gemm(const unsigned* __restrict__ aggb,
                                              const unsigned* __restrict__ hb,
                                              const unsigned* __restrict__ wtb,
                                              const float* __restrict__ bl,
                                              float* __restrict__ out) {
  int wave = threadIdx.x >> 6;
  int lane = threadIdx.x & 63;
  int m = lane & 15;
  int q = lane >> 4;
  int r0 = blockIdx.x * 64 + wave * 16;
  int rowA = r0 + m;
  if (rowA > N_NODES - 1) rowA = N_NODES - 1;  // tail clamp (stores guarded)

  const uint4* ar = (const uint4*)(aggb + (size_t)rowA * 64);
  const uint4* hr = (const uint4*)(hb + (size_t)rowA * 64);
  short8 afrag[8];
  #pragma unroll
  for (int kb = 0; kb < 4; ++kb) {
    uint4 u = ar[kb * 4 + q];
    afrag[kb] = *(short8*)&u;
  }
  #pragma unroll
  for (int kb = 0; kb < 4; ++kb) {
    uint4 u = hr[kb * 4 + q];
    afrag[kb + 4] = *(short8*)&u;
  }

  const uint4* b4 = (const uint4*)wtb;
  #pragma unroll
  for (int ct = 0; ct < 8; ++ct) {
    int c = ct * 16 + m;
    floatx4 acc = {0.0f, 0.0f, 0.0f, 0.0f};
    #pragma unroll
    for (int kb = 0; kb < 8; ++kb) {
      uint4 u = b4[kb * 512 + c * 4 + q];
      short8 bfrag = *(short8*)&u;
      acc = __builtin_amdgcn_mfma_f32_16x16x32_bf16(afrag[kb], bfrag, acc, 0, 0, 0);
    }
    float bias = bl[c];
    #pragma unroll
    for (int reg = 0; reg < 4; ++reg) {
      int r = r0 + q * 4 + reg;
      if (r < N_NODES) out[(size_t)r * DIM + c] = acc[reg] + bias;
    }
  }
}

extern "C" void kernel_launch(void* const* d_in, const int* in_sizes, int n_in,
                              void* d_out, int out_size, void* d_ws, size_t ws_size,
                              hipStream_t stream) {
  const float* x  = (const float*)d_in[0];
  const int*   ei = (const int*)d_in[1];   // [2, E] int32
  const float* lw = (const float*)d_in[2];
  const float* lb = (const float*)d_in[3];
  const float* Wl = (const float*)d_in[4];
  const float* bl = (const float*)d_in[5];
  const float* Wr = (const float*)d_in[6];
  float* out = (float*)d_out;

  char* ws = (char*)d_ws;
  unsigned* hb     = (unsigned*)(ws + HB_OFF);
  unsigned* wtb    = (unsigned*)(ws + WTB_OFF);
  int*      offs   = (int*)(ws + OFFS_OFF);
  int*      bhc    = (int*)(ws + BHC_OFF);
  int*      bh     = (int*)(ws + BH_OFF);
  int*      bsum   = (int*)(ws + BSUM_OFF);
  int*      binned = (int*)(ws + BIN_OFF);
  int*      srcidx = (int*)(ws + SRC_OFF);
  unsigned* aggb   = (unsigned*)(ws + AGGB_OFF);

  k_prep<<<N_NODES / 4, 256, 0, stream>>>(x, lw, lb, Wl, Wr, ei, hb, wtb, bhc);
  k_hscan1<<<HS_BLOCKS, 256, 0, stream>>>(bhc, bh, bsum);
  k_binsort<<<NB1, 256, 0, stream>>>(ei, bh, bhc, bsum, binned);
  k_csr<<<NBUCKET, 256, 0, stream>>>(bh, bsum, binned, offs, srcidx);
  k_gather<<<N_NODES / 8, 256, 0, stream>>>(hb, offs, srcidx, aggb);
  k_gemm<<<(N_NODES + 63) / 64, 256, 0, stream>>>(aggb, hb, wtb, bl, out);
}